// Round 7
// baseline (1767.164 us; speedup 1.0000x reference)
//
#include <hip/hip_runtime.h>
#include <hip/hip_bf16.h>
#include <math.h>

// Problem constants
#define BB 4
#define SS 2048
#define DM 1024
#define NH 8
#define DH 128
#define NE 8
#define NTOK (BB*SS)          // 8192
#define SCALE_SQRT 0.29730177875068026f

typedef unsigned short u16;
typedef short s8v __attribute__((ext_vector_type(8)));
typedef float f4v __attribute__((ext_vector_type(4)));
#define MFMA16(a,b,c) __builtin_amdgcn_mfma_f32_16x16x32_bf16((a),(b),(c),0,0,0)

// Round-to-nearest-even fp32 -> bf16 split: x ~= hi + lo (each bf16).
__device__ inline void bfsplit(float x, u16& h, u16& l) {
    unsigned u = __float_as_uint(x);
    unsigned hr = (u + 0x7FFFu + ((u >> 16) & 1u)) >> 16;
    h = (u16)hr;
    float hf = __uint_as_float(hr << 16);
    unsigned u2 = __float_as_uint(x - hf);
    l = (u16)((u2 + 0x7FFFu + ((u2 >> 16) & 1u)) >> 16);
}
__device__ inline u16 bf16rne(float x) {
    unsigned u = __float_as_uint(x);
    return (u16)((u + 0x7FFFu + ((u >> 16) & 1u)) >> 16);
}

// Async global->LDS 16B copy. LDS dest = wave-uniform base + lane*16.
__device__ inline void gll16(const u16* g, u16* l) {
    __builtin_amdgcn_global_load_lds(
        (const __attribute__((address_space(1))) unsigned int*)g,
        (__attribute__((address_space(3))) unsigned int*)l,
        16, 0, 0);
}

// Swizzled tile offset (u16 units) for [128][64]-u16 tiles staged linearly:
// row's 16B chunk c stored at chunk index c ^ (row&7). Same XOR on read.
__device__ inline int swzoff(int row, int kchunk) {
    return row * 64 + ((kchunk ^ (row & 7)) << 3);
}

// ---------------------------------------------------------------------------
// Projection GEMM via split-bf16 MFMA (3-term): out = scale * (x @ W^T).
// ---------------------------------------------------------------------------
__global__ __launch_bounds__(256, 2) void proj_mfma_kernel(
        const u16* __restrict__ Ah_g, const u16* __restrict__ Al_g,
        const u16* __restrict__ Bh_g, const u16* __restrict__ Bl_g,
        u16* __restrict__ out_h, u16* __restrict__ out_l, float scale) {
    const int i0 = blockIdx.x * 128;
    const int n0 = blockIdx.y * 128;
    __shared__ u16 Ah[128 * 64], Al[128 * 64], Bh[128 * 64], Bl[128 * 64];
    const int t = threadIdx.x;
    const int lane = t & 63, wave = t >> 6;
    const int wm = wave >> 1, wn = wave & 1;
    const int ln = lane & 15, qd = lane >> 4;
    const f4v z4 = {0.f, 0.f, 0.f, 0.f};

    f4v C[4][4];
#pragma unroll
    for (int fm = 0; fm < 4; ++fm)
#pragma unroll
        for (int fn = 0; fn < 4; ++fn) C[fm][fn] = z4;

    for (int kb = 0; kb < 16; ++kb) {
        __syncthreads();
        const int kbase = kb * 64;
#pragma unroll
        for (int p = 0; p < 4; ++p) {
            int chunk = p * 256 + t;
            int row = chunk >> 3;
            int cs  = ((chunk & 7) ^ (row & 7)) * 8;     // swizzled src col (u16)
            int ld  = (p * 256 + (t & 192)) * 8;         // wave-uniform LDS base
            size_t ga = (size_t)(i0 + row) * 1024 + kbase + cs;
            gll16(&Ah_g[ga], &Ah[ld]);
            gll16(&Al_g[ga], &Al[ld]);
            size_t gb = (size_t)(n0 + row) * 1024 + kbase + cs;
            gll16(&Bh_g[gb], &Bh[ld]);
            gll16(&Bl_g[gb], &Bl[ld]);
        }
        __syncthreads();
#pragma unroll
        for (int ks = 0; ks < 2; ++ks) {
            s8v ah[4], alv[4], bh[4], blv[4];
#pragma unroll
            for (int fm = 0; fm < 4; ++fm) {
                int o = swzoff(wm * 64 + fm * 16 + ln, ks * 4 + qd);
                ah[fm]  = *(const s8v*)&Ah[o];
                alv[fm] = *(const s8v*)&Al[o];
            }
#pragma unroll
            for (int fn = 0; fn < 4; ++fn) {
                int o = swzoff(wn * 64 + fn * 16 + ln, ks * 4 + qd);
                bh[fn]  = *(const s8v*)&Bh[o];
                blv[fn] = *(const s8v*)&Bl[o];
            }
#pragma unroll
            for (int fm = 0; fm < 4; ++fm)
#pragma unroll
                for (int fn = 0; fn < 4; ++fn) {
                    C[fm][fn] = MFMA16(ah[fm],  bh[fn],  C[fm][fn]);
                    C[fm][fn] = MFMA16(ah[fm],  blv[fn], C[fm][fn]);
                    C[fm][fn] = MFMA16(alv[fm], bh[fn],  C[fm][fn]);
                }
        }
    }
    const int h = n0 >> 7;
#pragma unroll
    for (int fm = 0; fm < 4; ++fm)
#pragma unroll
        for (int fn = 0; fn < 4; ++fn)
#pragma unroll
            for (int r = 0; r < 4; ++r) {
                int token = i0 + wm * 64 + fm * 16 + qd * 4 + r;
                int f = wn * 64 + fn * 16 + ln;
                int b = token >> 11, s = token & 2047;
                u16 hh, ll;
                bfsplit(C[fm][fn][r] * scale, hh, ll);
                size_t o = ((((size_t)(b * NH + h)) * SS + s) << 7) + f;
                out_h[o] = hh; out_l[o] = ll;
            }
}

// ---------------------------------------------------------------------------
// Gate: dense sparse-valued gate g[token][h][e]; float4 dot (same fma order
// as scalar loop -> identical results).
// ---------------------------------------------------------------------------
__global__ void gate_kernel(const float* __restrict__ x,
                            const float* __restrict__ sel,
                            float* __restrict__ gdense) {
    __shared__ float xs[DM];
    __shared__ float logits[64];
    __shared__ int   sbest[NH];
    __shared__ float sg1[NH], sg2[NH];
    const int token = blockIdx.x;
    const int t = threadIdx.x;  // 0..63
    const float4* xp4 = (const float4*)(x + (size_t)token * DM);
    float4* xs4 = (float4*)xs;
    for (int i = t; i < DM / 4; i += 64) xs4[i] = xp4[i];
    __syncthreads();
    const float4* sp4 = (const float4*)(sel + (size_t)t * DM);
    float acc = 0.f;
    for (int d = 0; d < DM / 4; ++d) {
        float4 a = xs4[d], b = sp4[d];
        acc += a.x * b.x; acc += a.y * b.y;
        acc += a.z * b.z; acc += a.w * b.w;
    }
    logits[t] = acc;
    __syncthreads();
    if (t < NH) {
        const float* lp = logits + t * NE;
        int best = 0; float bv = lp[0];
#pragma unroll
        for (int e = 1; e < NE - 1; ++e)
            if (lp[e] > bv) { bv = lp[e]; best = e; }   // strict > == lowest idx tie
        sbest[t] = best;
        sg1[t] = 1.f / (1.f + expf(-bv));
        sg2[t] = 1.f / (1.f + expf(-lp[NE - 1]));
    }
    __syncthreads();
    const int h = t >> 3, e = t & 7;
    float val = (e == sbest[h]) ? sg1[h] : ((e == NE - 1) ? sg2[h] : 0.f);
    gdense[(size_t)token * 64 + t] = val;
}

// ---------------------------------------------------------------------------
// Preprocess: split fp32 -> bf16 hi/lo (no transpose). n divisible by 1024.
// ---------------------------------------------------------------------------
__global__ void split_kernel(const float* __restrict__ src,
                             u16* __restrict__ dh, u16* __restrict__ dl) {
    int i = (blockIdx.x * 256 + threadIdx.x) * 4;
    float4 v = *(const float4*)(src + i);
    u16 h[4], l[4];
    bfsplit(v.x, h[0], l[0]); bfsplit(v.y, h[1], l[1]);
    bfsplit(v.z, h[2], l[2]); bfsplit(v.w, h[3], l[3]);
    uint2 ph = { (unsigned)h[0] | ((unsigned)h[1] << 16),
                 (unsigned)h[2] | ((unsigned)h[3] << 16) };
    uint2 pl = { (unsigned)l[0] | ((unsigned)l[1] << 16),
                 (unsigned)l[2] | ((unsigned)l[3] << 16) };
    *(uint2*)&dh[i] = ph;
    *(uint2*)&dl[i] = pl;
}

// ---------------------------------------------------------------------------
// Preprocess: per-matrix transpose + split. src[mat][R][C] -> dst[mat][C][R].
// ---------------------------------------------------------------------------
__global__ void tsplit_kernel(const float* __restrict__ src,
                              u16* __restrict__ dh, u16* __restrict__ dl,
                              int R, int C) {
    __shared__ float tile[32][33];
    const int mat = blockIdx.x;
    const int r0 = blockIdx.y * 32, c0 = blockIdx.z * 32;
    const size_t base = (size_t)mat * R * C;
    const int tr = threadIdx.x >> 5, tc = threadIdx.x & 31;
#pragma unroll
    for (int p = 0; p < 4; ++p)
        tile[tr + p * 8][tc] = src[base + (size_t)(r0 + tr + p * 8) * C + c0 + tc];
    __syncthreads();
#pragma unroll
    for (int p = 0; p < 4; ++p) {
        int cc = tr + p * 8, rr = tc;
        float x = tile[rr][cc];
        u16 hh, ll; bfsplit(x, hh, ll);
        size_t o = base + (size_t)(c0 + cc) * R + r0 + rr;
        dh[o] = hh; dl[o] = ll;
    }
}

// ---------------------------------------------------------------------------
// Value CVMM, split-bf16 MFMA, dense over experts (round-5 version).
// ---------------------------------------------------------------------------
__global__ __launch_bounds__(256, 2) void v_mfma_kernel(
        const u16* __restrict__ Ah_g, const u16* __restrict__ Al_g,
        const u16* __restrict__ Bh_g, const u16* __restrict__ Bl_g,
        const float* __restrict__ gdense,
        float* __restrict__ wv) {
    const int i0 = blockIdx.x * 128;
    const int h  = blockIdx.y;
    __shared__ u16 Ah[128 * 64], Al[128 * 64], Bh[128 * 64], Bl[128 * 64];
    __shared__ float gl[128 * 8];
    const int t = threadIdx.x;
    const int lane = t & 63, wave = t >> 6;
    const int wm = wave >> 1, wn = wave & 1;
    const int ln = lane & 15, qd = lane >> 4;
    const f4v z4 = {0.f, 0.f, 0.f, 0.f};

#pragma unroll
    for (int p = 0; p < 4; ++p) {
        int idx = p * 256 + t;
        gl[idx] = gdense[(size_t)(i0 + (idx >> 3)) * 64 + h * 8 + (idx & 7)];
    }

    f4v C[4][4];
#pragma unroll
    for (int fm = 0; fm < 4; ++fm)
#pragma unroll
        for (int fn = 0; fn < 4; ++fn) C[fm][fn] = z4;

    for (int e = 0; e < 8; ++e) {
        f4v T[4][4];
#pragma unroll
        for (int fm = 0; fm < 4; ++fm)
#pragma unroll
            for (int fn = 0; fn < 4; ++fn) T[fm][fn] = z4;
        const size_t bbase = (size_t)(h * 8 + e) * DH * 1024;
        for (int kb = 0; kb < 16; ++kb) {
            __syncthreads();
            const int kbase = kb * 64;
#pragma unroll
            for (int p = 0; p < 4; ++p) {
                int chunk = p * 256 + t;
                int row = chunk >> 3;
                int cs  = ((chunk & 7) ^ (row & 7)) * 8;
                int ld  = (p * 256 + (t & 192)) * 8;
                size_t ga = (size_t)(i0 + row) * 1024 + kbase + cs;
                gll16(&Ah_g[ga], &Ah[ld]);
                gll16(&Al_g[ga], &Al[ld]);
                size_t gb = bbase + (size_t)row * 1024 + kbase + cs;
                gll16(&Bh_g[gb], &Bh[ld]);
                gll16(&Bl_g[gb], &Bl[ld]);
            }
            __syncthreads();
#pragma unroll
            for (int ks = 0; ks < 2; ++ks) {
                s8v ah[4], alv[4], bh[4], blv[4];
#pragma unroll
                for (int fm = 0; fm < 4; ++fm) {
                    int o = swzoff(wm * 64 + fm * 16 + ln, ks * 4 + qd);
                    ah[fm]  = *(const s8v*)&Ah[o];
                    alv[fm] = *(const s8v*)&Al[o];
                }
#pragma unroll
                for (int fn = 0; fn < 4; ++fn) {
                    int o = swzoff(wn * 64 + fn * 16 + ln, ks * 4 + qd);
                    bh[fn]  = *(const s8v*)&Bh[o];
                    blv[fn] = *(const s8v*)&Bl[o];
                }
#pragma unroll
                for (int fm = 0; fm < 4; ++fm)
#pragma unroll
                    for (int fn = 0; fn < 4; ++fn) {
                        T[fm][fn] = MFMA16(ah[fm],  bh[fn],  T[fm][fn]);
                        T[fm][fn] = MFMA16(ah[fm],  blv[fn], T[fm][fn]);
                        T[fm][fn] = MFMA16(alv[fm], bh[fn],  T[fm][fn]);
                    }
            }
        }
#pragma unroll
        for (int fm = 0; fm < 4; ++fm)
#pragma unroll
            for (int r = 0; r < 4; ++r) {
                float g = gl[(wm * 64 + fm * 16 + qd * 4 + r) * 8 + e];
#pragma unroll
                for (int fn = 0; fn < 4; ++fn)
                    C[fm][fn][r] += g * T[fm][fn][r];
            }
    }
#pragma unroll
    for (int fm = 0; fm < 4; ++fm)
#pragma unroll
        for (int fn = 0; fn < 4; ++fn)
#pragma unroll
            for (int r = 0; r < 4; ++r) {
                int token = i0 + wm * 64 + fm * 16 + qd * 4 + r;
                int f = wn * 64 + fn * 16 + ln;
                int b = token >> 11, s = token & 2047;
                wv[(((size_t)(b * NH + h) * SS + s) << 7) + f] = C[fm][fn][r];
            }
}

// ---------------------------------------------------------------------------
// Output CVMM, split-bf16 MFMA, dense over (h,e).
// 1D grid 512 with bijective XCD-aware remap: consecutive blockIdx round-robin
// XCDs (xcd = id&7), so map each XCD to 8 full i-tiles (all 8 n-tiles each):
// the 8 blocks sharing an A-tile land on ONE XCD -> A fetched once per L2.
// ---------------------------------------------------------------------------
__global__ __launch_bounds__(256, 2) void out_mfma_kernel(
        const u16* __restrict__ Ah_g, const u16* __restrict__ Al_g,
        const u16* __restrict__ Bh_g, const u16* __restrict__ Bl_g,
        const float* __restrict__ gdense,
        float* __restrict__ out) {
    const int id = blockIdx.x;               // 0..511
    const int xcd = id & 7, j = id >> 3;
    const int it = xcd * 8 + (j & 7);        // i-tile 0..63 (8 per XCD)
    const int nt = j >> 3;                   // n-tile 0..7
    const int n0 = nt * 128;
    const int i0 = it * 128;
    __shared__ u16 Ah[128 * 64], Al[128 * 64], Bh[128 * 64], Bl[128 * 64];
    __shared__ float gl[128 * 8];
    const int t = threadIdx.x;
    const int lane = t & 63, wave = t >> 6;
    const int wm = wave >> 1, wn = wave & 1;
    const int ln = lane & 15, qd = lane >> 4;
    const f4v z4 = {0.f, 0.f, 0.f, 0.f};

    f4v C[4][4];
#pragma unroll
    for (int fm = 0; fm < 4; ++fm)
#pragma unroll
        for (int fn = 0; fn < 4; ++fn) C[fm][fn] = z4;

    for (int h = 0; h < 8; ++h) {
        __syncthreads();
#pragma unroll
        for (int p = 0; p < 4; ++p) {
            int idx = p * 256 + t;
            gl[idx] = gdense[(size_t)(i0 + (idx >> 3)) * 64 + h * 8 + (idx & 7)];
        }
        for (int e = 0; e < 8; ++e) {
            f4v T[4][4];
#pragma unroll
            for (int fm = 0; fm < 4; ++fm)
#pragma unroll
                for (int fn = 0; fn < 4; ++fn) T[fm][fn] = z4;
            const size_t bbase = ((size_t)(h * 8 + e) * 1024 + n0) * DH;
#pragma unroll
            for (int kb = 0; kb < 2; ++kb) {
                __syncthreads();
                const int ka = h * 128 + kb * 64;
                const int kbb = kb * 64;
#pragma unroll
                for (int p = 0; p < 4; ++p) {
                    int chunk = p * 256 + t;
                    int row = chunk >> 3;
                    int cs  = ((chunk & 7) ^ (row & 7)) * 8;
                    int ld  = (p * 256 + (t & 192)) * 8;
                    size_t ga = (size_t)(i0 + row) * 1024 + ka + cs;
                    gll16(&Ah_g[ga], &Ah[ld]);
                    gll16(&Al_g[ga], &Al[ld]);
                    size_t gb = bbase + (size_t)row * DH + kbb + cs;
                    gll16(&Bh_g[gb], &Bh[ld]);
                    gll16(&Bl_g[gb], &Bl[ld]);
                }
                __syncthreads();
#pragma unroll
                for (int ks = 0; ks < 2; ++ks) {
                    s8v ah[4], alv[4], bh[4], blv[4];
#pragma unroll
                    for (int fm = 0; fm < 4; ++fm) {
                        int o = swzoff(wm * 64 + fm * 16 + ln, ks * 4 + qd);
                        ah[fm]  = *(const s8v*)&Ah[o];
                        alv[fm] = *(const s8v*)&Al[o];
                    }
#pragma unroll
                    for (int fn = 0; fn < 4; ++fn) {
                        int o = swzoff(wn * 64 + fn * 16 + ln, ks * 4 + qd);
                        bh[fn]  = *(const s8v*)&Bh[o];
                        blv[fn] = *(const s8v*)&Bl[o];
                    }
#pragma unroll
                    for (int fm = 0; fm < 4; ++fm)
#pragma unroll
                        for (int fn = 0; fn < 4; ++fn) {
                            T[fm][fn] = MFMA16(ah[fm],  bh[fn],  T[fm][fn]);
                            T[fm][fn] = MFMA16(ah[fm],  blv[fn], T[fm][fn]);
                            T[fm][fn] = MFMA16(alv[fm], bh[fn],  T[fm][fn]);
                        }
                }
            }
#pragma unroll
            for (int fm = 0; fm < 4; ++fm)
#pragma unroll
                for (int r = 0; r < 4; ++r) {
                    float g = gl[(wm * 64 + fm * 16 + qd * 4 + r) * 8 + e];
#pragma unroll
                    for (int fn = 0; fn < 4; ++fn)
                        C[fm][fn][r] += g * T[fm][fn][r];
                }
        }
    }
#pragma unroll
    for (int fm = 0; fm < 4; ++fm)
#pragma unroll
        for (int fn = 0; fn < 4; ++fn)
#pragma unroll
            for (int r = 0; r < 4; ++r) {
                int token = i0 + wm * 64 + fm * 16 + qd * 4 + r;
                int d = n0 + wn * 64 + fn * 16 + ln;
                out[(size_t)token * DM + d] = C[fm][fn][r];
            }
}

// ---------------------------------------------------------------------------
// MFMA flash attention (unchanged from round 5).
// ---------------------------------------------------------------------------
__global__ __launch_bounds__(256, 2) void attn_mfma_kernel(
        const u16* __restrict__ qh, const u16* __restrict__ ql,
        const u16* __restrict__ kh, const u16* __restrict__ kl,
        const u16* __restrict__ vth, const u16* __restrict__ vtl,
        u16* __restrict__ res_hi, u16* __restrict__ res_lo) {
    const int bid = blockIdx.x;          // bh*16 + qtile
    const int bh = bid >> 4;
    const int q0 = (bid & 15) * 128;

    __shared__ u16 Ksh[32 * 136];        // 8704 B
    __shared__ u16 Ksl[32 * 136];
    __shared__ u16 Vsh[128 * 40];        // 10240 B
    __shared__ u16 Vsl[128 * 40];
    __shared__ u16 Ps[4][32 * 40];       // 10240 B  -> total 48128 B

    const int t = threadIdx.x;
    const int lane = t & 63, w = t >> 6;
    const int ln = lane & 15, qd = lane >> 4;

    // Q A-fragments in registers: 2 row-blocks of 16 (m = ln within block)
    s8v Qh[2][4], Qlv[2][4];
#pragma unroll
    for (int fm = 0; fm < 2; ++fm) {
        const size_t qoff = ((size_t)bh * SS + q0 + w * 32 + fm * 16 + ln) * DH;
        const u16* qhp = qh + qoff;
        const u16* qlp = ql + qoff;
#pragma unroll
        for (int ks = 0; ks < 4; ++ks) {
            Qh[fm][ks]  = *(const s8v*)(qhp + ks * 32 + qd * 8);
            Qlv[fm][ks] = *(const s8v*)(qlp + ks * 32 + qd * 8);
        }
    }

    f4v Of[2][8];
    const f4v z4 = {0.f, 0.f, 0.f, 0.f};
#pragma unroll
    for (int fm = 0; fm < 2; ++fm)
#pragma unroll
        for (int fn = 0; fn < 8; ++fn) Of[fm][fn] = z4;
    float mrow[2][4], lrow[2][4];
#pragma unroll
    for (int fm = 0; fm < 2; ++fm)
#pragma unroll
        for (int r = 0; r < 4; ++r) { mrow[fm][r] = -INFINITY; lrow[fm][r] = 0.f; }

    const u16* kbh = kh + (size_t)bh * SS * DH;
    const u16* kbl = kl + (size_t)bh * SS * DH;
    const u16* vbh = vth + (size_t)bh * DH * SS;   // [f][s]
    const u16* vbl = vtl + (size_t)bh * DH * SS;

    // per-thread staging addresses (chunk = t and chunk = 256+t)
    const int krow0 = t >> 4,        kc0 = t & 15;
    const int krow1 = (256 + t) >> 4, kc1 = (256 + t) & 15;
    const int vrow0 = t >> 2,        vc0 = t & 3;
    const int vrow1 = (256 + t) >> 2, vc1 = (256 + t) & 3;
    const int kld0 = krow0 * 136 + kc0 * 8, kld1 = krow1 * 136 + kc1 * 8;
    const int vld0 = vrow0 * 40 + vc0 * 8,  vld1 = vrow1 * 40 + vc1 * 8;

    // staging registers — NAMED scalars, straight-line code (no arrays)
    uint4 rKh0, rKh1, rKl0, rKl1, rVh0, rVh1, rVl0, rVl1;

#define LOADREGS(KT)                                                         \
    {                                                                        \
        size_t g0 = (size_t)((KT) * 32 + krow0) * DH + kc0 * 8;              \
        size_t g1 = (size_t)((KT) * 32 + krow1) * DH + kc1 * 8;              \
        rKh0 = *(const uint4*)&kbh[g0];  rKl0 = *(const uint4*)&kbl[g0];     \
        rKh1 = *(const uint4*)&kbh[g1];  rKl1 = *(const uint4*)&kbl[g1];     \
        size_t v0 = (size_t)vrow0 * SS + (KT) * 32 + vc0 * 8;                \
        size_t v1 = (size_t)vrow1 * SS + (KT) * 32 + vc1 * 8;                \
        rVh0 = *(const uint4*)&vbh[v0];  rVl0 = *(const uint4*)&vbl[v0];     \
        rVh1 = *(const uint4*)&vbh[v1];  rVl1 = *(const uint4*)&vbl[v1];     \
    }

#define STORELDS()                                                           \
    {                                                                        \
        *(uint4*)&Ksh[kld0] = rKh0;  *(uint4*)&Ksl[kld0] = rKl0;             \
        *(uint4*)&Ksh[kld1] = rKh1;  *(uint4*)&Ksl[kld1] = rKl1;             \
        *(uint4*)&Vsh[vld0] = rVh0;  *(uint4*)&Vsl[vld0] = rVl0;             \
        *(uint4*)&Vsh[vld1] = rVh1;  *(uint4*)&Vsl[vld1] = rVl1;             \
    }

    // prologue: stage tile 0
    LOADREGS(0);
    STORELDS();
    __syncthreads();

    for (int kt = 0; kt < SS / 32; ++kt) {
        const bool more = (kt + 1 < SS / 32);
        if (more) LOADREGS(kt + 1);       // in flight during compute

        // ---- QK^T: S[fm][nt], K frags shared across the 2 row-blocks ----
        f4v S[2][2];
#pragma unroll
        for (int fm = 0; fm < 2; ++fm)
#pragma unroll
            for (int nt = 0; nt < 2; ++nt) S[fm][nt] = z4;
#pragma unroll
        for (int ks = 0; ks < 4; ++ks) {
#pragma unroll
            for (int nt = 0; nt < 2; ++nt) {
                int o = (nt * 16 + ln) * 136 + ks * 32 + qd * 8;
                s8v kbhf = *(const s8v*)&Ksh[o];
                s8v kblf = *(const s8v*)&Ksl[o];
#pragma unroll
                for (int fm = 0; fm < 2; ++fm) {
                    S[fm][nt] = MFMA16(Qh[fm][ks],  kbhf, S[fm][nt]);
                    S[fm][nt] = MFMA16(Qh[fm][ks],  kblf, S[fm][nt]);
                    S[fm][nt] = MFMA16(Qlv[fm][ks], kbhf, S[fm][nt]);
                }
            }
        }

        // ---- online softmax (two independent row-blocks -> ILP) ----
        float pv[2][2][4];
#pragma unroll
        for (int fm = 0; fm < 2; ++fm) {
            float mt[4];
#pragma unroll
            for (int r = 0; r < 4; ++r) mt[r] = fmaxf(S[fm][0][r], S[fm][1][r]);
#pragma unroll
            for (int mask = 1; mask < 16; mask <<= 1)
#pragma unroll
                for (int r = 0; r < 4; ++r)
                    mt[r] = fmaxf(mt[r], __shfl_xor(mt[r], mask, 64));
            float alpha[4];
#pragma unroll
            for (int r = 0; r < 4; ++r) {
                float mn = fmaxf(mrow[fm][r], mt[r]);
                alpha[r] = __expf(mrow[fm][r] - mn);
                mrow[fm][r] = mn;
            }
            float lt[4] = {0.f, 0.f, 0.f, 0.f};
#pragma unroll
            for (int nt = 0; nt < 2; ++nt)
#pragma unroll
                for (int r = 0; r < 4; ++r) {
                    float p = __expf(S[fm][nt][r] - mrow[fm][r]);
                    pv[fm][nt][r] = p;
                    lt[r] += p;
                }
#pragma unroll
            for (int mask = 1; mask < 16; mask <<= 1)
#pragma unroll
                for (int r = 0; r < 4; ++r)
                    lt[r] += __shfl_xor(lt[r], mask, 64);
#pragma unroll
            for (int r = 0; r < 4; ++r)
                lrow[fm][r] = alpha[r] * lrow[fm][r] + lt[r];
#pragma unroll
            for (int fn = 0; fn < 8; ++fn)
#pragma unroll
                for (int r = 0; r < 4; ++r) Of[fm][fn][r] *= alpha[r];
        }

        // ---- P (C-layout) -> per-wave LDS (A-layout source) ----
#pragma unroll
        for (int fm = 0; fm < 2; ++fm)
#pragma unroll
            for (int nt = 0; nt < 2; ++nt)
#pragma unroll
                for (int r = 0; r < 4; ++r)
                    Ps[w][(fm * 16 + qd * 4 + r) * 40 + nt * 16 + ln] =
                        bf16rne(pv[fm][nt][r]);
        // same-wave write->read: compiler inserts lgkmcnt wait; no barrier.

        // ---- PV: Of += P * V, V frags shared across the 2 row-blocks ----
        s8v pf[2];
#pragma unroll
        for (int fm = 0; fm < 2; ++fm)
            pf[fm] = *(const s8v*)&Ps[w][(fm * 16 + ln) * 40 + qd * 8];
#pragma unroll
        for (int fn = 0; fn < 8; ++fn) {
            int o = (fn * 16 + ln) * 40 + qd * 8;
            s8v vbhf = *(const s8v*)&Vsh[o];
            s8v vblf = *(const s8v*)&Vsl[o];
#pragma unroll
            for (int fm = 0; fm < 2; ++fm) {
                Of[fm][fn] = MFMA16(pf[fm], vbhf, Of[fm][fn]);
                Of[fm][fn] = MFMA16(pf[fm], vblf, Of[fm][fn]);
            }
        }

        __syncthreads();                  // all waves done reading K/V LDS
        if (more) {
            STORELDS();                   // waits vmcnt for rK/rV arrival
            __syncthreads();              // next tile staged
        }
    }

    // ---- epilogue: normalize, split to bf16 hi/lo, store res[token][1024] --
    const int b = bh >> 3, h = bh & 7;
#pragma unroll
    for (int fm = 0; fm < 2; ++fm)
#pragma unroll
        for (int r = 0; r < 4; ++r) {
            float linv = 1.f / lrow[fm][r];
            int qi = q0 + w * 32 + fm * 16 + qd * 4 + r;
            size_t off = (size_t)(b * SS + qi) * DM + h * DH + ln;
#pragma unroll
            for (int fn = 0; fn < 8; ++fn) {
                u16 hh, ll;
                bfsplit(Of[fm][fn][r] * linv, hh, ll);
                res_hi[off + fn * 16] = hh;
                res_lo[off + fn * 16] = ll;
            }
        }
#undef LOADREGS
#undef STORELDS
}

// ---------------------------------------------------------------------------
extern "C" void kernel_launch(void* const* d_in, const int* in_sizes, int n_in,
                              void* d_out, int out_size, void* d_ws, size_t ws_size,
                              hipStream_t stream) {
    (void)in_sizes; (void)n_in; (void)out_size; (void)ws_size;
    const float* q_src = (const float*)d_in[0];
    const float* k_src = (const float*)d_in[1];
    const float* v_src = (const float*)d_in[2];
    const float* Wq    = (const float*)d_in[3];
    const float* Wk    = (const float*)d_in[4];
    const float* V     = (const float*)d_in[5];
    const float* O     = (const float*)d_in[6];
    const float* sel_v = (const float*)d_in[7];
    const float* sel_o = (const float*)d_in[8];
    float* out = (float*)d_out;

    // workspace layout
    const size_t NELT = (size_t)NTOK * DM;   // 8388608
    u16* wq_h = (u16*)d_ws;                  // q hi/lo [bh][s][f]
    u16* wq_l = wq_h + NELT;
    u16* wk_h = wq_l + NELT;                 // k hi/lo
    u16* wk_l = wk_h + NELT;
    float* wv = (float*)(wk_l + NELT);       // v fp32 [bh][s][f]
    u16* res_hi = (u16*)(wv + NELT);         // attention result hi/lo
    u16* res_lo = res_hi + NELT;
    u16* vs_hi  = res_lo + NELT;             // vsrc split (later: Ot)
    u16* vs_lo  = vs_hi + NELT;
    u16* Vt_hi  = vs_lo + NELT;              // V transposed (later: vT)
    u16* Vt_lo  = Vt_hi + NELT;
    float* gv = (float*)(Vt_lo + NELT);      // dense gates [8192][64]
    float* go = gv + (size_t)NTOK * 64;
    u16* Wq_h = (u16*)(go + (size_t)NTOK * 64);  // W splits (1024x1024 each)
    u16* Wq_l = Wq_h + (size_t)DM * DM;
    u16* Wk_h = Wq_l + (size_t)DM * DM;
    u16* Wk_l = Wk_h + (size_t)DM * DM;
    // aliases (regions dead during the phase they are used)
    u16* qsrc_h = res_hi;                    // dead until attn writes res
    u16* qsrc_l = res_lo;
    u16* ksrc_h = (u16*)wv;                  // dead until v_mfma writes wv
    u16* ksrc_l = ksrc_h + NELT;
    u16* Ot_hi = vs_hi;                      // alias (dead after v_mfma)
    u16* Ot_lo = vs_lo;
    u16* vth   = Vt_hi;                      // alias (dead after v_mfma)
    u16* vtl   = Vt_lo;

    // preprocess: splits
    split_kernel<<<NELT / 1024, 256, 0, stream>>>(v_src, vs_hi, vs_lo);
    split_kernel<<<NELT / 1024, 256, 0, stream>>>(q_src, qsrc_h, qsrc_l);
    split_kernel<<<NELT / 1024, 256, 0, stream>>>(k_src, ksrc_h, ksrc_l);
    split_kernel<<<(DM * DM) / 1024, 256, 0, stream>>>(Wq, Wq_h, Wq_l);
    split_kernel<<<(DM * DM) / 1024, 256, 0, stream>>>(Wk, Wk_h, Wk_l);
    tsplit_kernel<<<dim3(64, 32, 4), 256, 0, stream>>>(V, Vt_hi, Vt_lo, 1024, 128);

    // gates
    gate_kernel<<<NTOK, 64, 0, stream>>>(k_src, sel_v, gv);
    gate_kernel<<<NTOK, 64, 0, stream>>>(q_src, sel_o, go);

    // q/k projections via MFMA (emit bf16 hi/lo)
    proj_mfma_kernel<<<dim3(64, 8), 256, 0, stream>>>(
        qsrc_h, qsrc_l, Wq_h, Wq_l, wq_h, wq_l, SCALE_SQRT);
    proj_mfma_kernel<<<dim3(64, 8), 256, 0, stream>>>(
        ksrc_h, ksrc_l, Wk_h, Wk_l, wk_h, wk_l, SCALE_SQRT);

    // value CVMM (MFMA, dense) -> wv fp32 (overwrites ksrc splits: proj done)
    v_mfma_kernel<<<dim3(64, 8), 256, 0, stream>>>(vs_hi, vs_lo, Vt_hi, Vt_lo, gv, wv);

    // transpose+split O into dead vsrc buffers
    tsplit_kernel<<<dim3(64, 4, 32), 256, 0, stream>>>(O, Ot_hi, Ot_lo, 128, 1024);

    // transpose+split v into dead Vt buffers: vT[bh][f][s]
    tsplit_kernel<<<dim3(32, 64, 4), 256, 0, stream>>>(wv, vth, vtl, 2048, 128);

    // attention (MFMA flash; 128-query tiles; writes res = overwrites qsrc)
    attn_mfma_kernel<<<BB * NH * (SS / 128), 256, 0, stream>>>(
        wq_h, wq_l, wk_h, wk_l, vth, vtl, res_hi, res_lo);

    // output CVMM (MFMA, dense; XCD-swizzled 1D grid)
    out_mfma_kernel<<<512, 256, 0, stream>>>(res_hi, res_lo, Ot_hi, Ot_lo, go, out);
}

// Round 8
// 1393.552 us; speedup vs baseline: 1.2681x; 1.2681x over previous
//
#include <hip/hip_runtime.h>
#include <hip/hip_bf16.h>
#include <math.h>

// Problem constants
#define BB 4
#define SS 2048
#define DM 1024
#define NH 8
#define DH 128
#define NE 8
#define NTOK (BB*SS)          // 8192
#define SCALE_SQRT 0.29730177875068026f

typedef unsigned short u16;
typedef short s8v __attribute__((ext_vector_type(8)));
typedef float f4v __attribute__((ext_vector_type(4)));
#define MFMA16(a,b,c) __builtin_amdgcn_mfma_f32_16x16x32_bf16((a),(b),(c),0,0,0)

// Round-to-nearest-even fp32 -> bf16 split: x ~= hi + lo (each bf16).
__device__ inline void bfsplit(float x, u16& h, u16& l) {
    unsigned u = __float_as_uint(x);
    unsigned hr = (u + 0x7FFFu + ((u >> 16) & 1u)) >> 16;
    h = (u16)hr;
    float hf = __uint_as_float(hr << 16);
    unsigned u2 = __float_as_uint(x - hf);
    l = (u16)((u2 + 0x7FFFu + ((u2 >> 16) & 1u)) >> 16);
}
__device__ inline u16 bf16rne(float x) {
    unsigned u = __float_as_uint(x);
    return (u16)((u + 0x7FFFu + ((u >> 16) & 1u)) >> 16);
}

// Async global->LDS 16B copy. LDS dest = wave-uniform base + lane*16.
__device__ inline void gll16(const u16* g, u16* l) {
    __builtin_amdgcn_global_load_lds(
        (const __attribute__((address_space(1))) unsigned int*)g,
        (__attribute__((address_space(3))) unsigned int*)l,
        16, 0, 0);
}

// Swizzled tile offset (u16 units) for [128][64]-u16 tiles staged linearly:
// row's 16B chunk c stored at chunk index c ^ (row&7). Same XOR on read.
__device__ inline int swzoff(int row, int kchunk) {
    return row * 64 + ((kchunk ^ (row & 7)) << 3);
}

// ---------------------------------------------------------------------------
// Projection GEMM via split-bf16 MFMA (3-term): out = scale * (x @ W^T).
// ---------------------------------------------------------------------------
__global__ __launch_bounds__(256, 2) void proj_mfma_kernel(
        const u16* __restrict__ Ah_g, const u16* __restrict__ Al_g,
        const u16* __restrict__ Bh_g, const u16* __restrict__ Bl_g,
        u16* __restrict__ out_h, u16* __restrict__ out_l, float scale) {
    const int i0 = blockIdx.x * 128;
    const int n0 = blockIdx.y * 128;
    __shared__ u16 Ah[128 * 64], Al[128 * 64], Bh[128 * 64], Bl[128 * 64];
    const int t = threadIdx.x;
    const int lane = t & 63, wave = t >> 6;
    const int wm = wave >> 1, wn = wave & 1;
    const int ln = lane & 15, qd = lane >> 4;
    const f4v z4 = {0.f, 0.f, 0.f, 0.f};

    f4v C[4][4];
#pragma unroll
    for (int fm = 0; fm < 4; ++fm)
#pragma unroll
        for (int fn = 0; fn < 4; ++fn) C[fm][fn] = z4;

    for (int kb = 0; kb < 16; ++kb) {
        __syncthreads();
        const int kbase = kb * 64;
#pragma unroll
        for (int p = 0; p < 4; ++p) {
            int chunk = p * 256 + t;
            int row = chunk >> 3;
            int cs  = ((chunk & 7) ^ (row & 7)) * 8;     // swizzled src col (u16)
            int ld  = (p * 256 + (t & 192)) * 8;         // wave-uniform LDS base
            size_t ga = (size_t)(i0 + row) * 1024 + kbase + cs;
            gll16(&Ah_g[ga], &Ah[ld]);
            gll16(&Al_g[ga], &Al[ld]);
            size_t gb = (size_t)(n0 + row) * 1024 + kbase + cs;
            gll16(&Bh_g[gb], &Bh[ld]);
            gll16(&Bl_g[gb], &Bl[ld]);
        }
        __syncthreads();
#pragma unroll
        for (int ks = 0; ks < 2; ++ks) {
            s8v ah[4], alv[4], bh[4], blv[4];
#pragma unroll
            for (int fm = 0; fm < 4; ++fm) {
                int o = swzoff(wm * 64 + fm * 16 + ln, ks * 4 + qd);
                ah[fm]  = *(const s8v*)&Ah[o];
                alv[fm] = *(const s8v*)&Al[o];
            }
#pragma unroll
            for (int fn = 0; fn < 4; ++fn) {
                int o = swzoff(wn * 64 + fn * 16 + ln, ks * 4 + qd);
                bh[fn]  = *(const s8v*)&Bh[o];
                blv[fn] = *(const s8v*)&Bl[o];
            }
#pragma unroll
            for (int fm = 0; fm < 4; ++fm)
#pragma unroll
                for (int fn = 0; fn < 4; ++fn) {
                    C[fm][fn] = MFMA16(ah[fm],  bh[fn],  C[fm][fn]);
                    C[fm][fn] = MFMA16(ah[fm],  blv[fn], C[fm][fn]);
                    C[fm][fn] = MFMA16(alv[fm], bh[fn],  C[fm][fn]);
                }
        }
    }
    const int h = n0 >> 7;
#pragma unroll
    for (int fm = 0; fm < 4; ++fm)
#pragma unroll
        for (int fn = 0; fn < 4; ++fn)
#pragma unroll
            for (int r = 0; r < 4; ++r) {
                int token = i0 + wm * 64 + fm * 16 + qd * 4 + r;
                int f = wn * 64 + fn * 16 + ln;
                int b = token >> 11, s = token & 2047;
                u16 hh, ll;
                bfsplit(C[fm][fn][r] * scale, hh, ll);
                size_t o = ((((size_t)(b * NH + h)) * SS + s) << 7) + f;
                out_h[o] = hh; out_l[o] = ll;
            }
}

// ---------------------------------------------------------------------------
// Fused gate: 64-token x 64-expert fp32 logit tile (GEMM-tiled, sel read
// 128x not 8192x) + in-block argmax/sigmoid/sparse-gdense epilogue.
// Per-output accumulation chain is ascending-d — bit-identical to the old
// per-token scalar gate. grid (128 token-tiles, 2 gates).
// ---------------------------------------------------------------------------
__global__ __launch_bounds__(256) void gate_fused_kernel(
        const float* __restrict__ xk, const float* __restrict__ selv,
        float* __restrict__ gvd,
        const float* __restrict__ xq, const float* __restrict__ selo,
        float* __restrict__ god) {
    const float* x   = blockIdx.y ? xq  : xk;
    const float* sel = blockIdx.y ? selo : selv;
    float* gd        = blockIdx.y ? god : gvd;
    __shared__ float As[16][65];
    __shared__ float Ws[16][65];
    __shared__ float lt[64][72];
    const int t  = threadIdx.x;
    const int tx = t & 15, ty = t >> 4;
    const int m0 = blockIdx.x * 64;
    float acc[4][4] = {};
    for (int kt = 0; kt < DM; kt += 16) {
        __syncthreads();
#pragma unroll
        for (int i = 0; i < 4; ++i) {
            int idx = t + i * 256;
            int m = idx >> 4, kk = idx & 15;
            As[kk][m] = x[(size_t)(m0 + m) * DM + kt + kk];
            Ws[kk][m] = sel[(size_t)m * DM + kt + kk];
        }
        __syncthreads();
#pragma unroll
        for (int kk = 0; kk < 16; ++kk) {
            float a[4], b[4];
#pragma unroll
            for (int i = 0; i < 4; ++i) a[i] = As[kk][ty * 4 + i];
#pragma unroll
            for (int j = 0; j < 4; ++j) b[j] = Ws[kk][tx * 4 + j];
#pragma unroll
            for (int i = 0; i < 4; ++i)
#pragma unroll
                for (int j = 0; j < 4; ++j) acc[i][j] += a[i] * b[j];
        }
    }
    __syncthreads();
#pragma unroll
    for (int i = 0; i < 4; ++i)
#pragma unroll
        for (int j = 0; j < 4; ++j)
            lt[ty * 4 + i][tx * 4 + j] = acc[i][j];
    __syncthreads();
    // epilogue: 512 (token,h) pairs, 2 per thread
#pragma unroll
    for (int pp = 0; pp < 2; ++pp) {
        int pair = pp * 256 + t;
        int tok = pair >> 3, hh = pair & 7;
        const float* lp = &lt[tok][hh * 8];
        int best = 0; float bv = lp[0];
#pragma unroll
        for (int e = 1; e < NE - 1; ++e)
            if (lp[e] > bv) { bv = lp[e]; best = e; }   // strict > == lowest idx tie
        float g1 = 1.f / (1.f + expf(-bv));
        float g2 = 1.f / (1.f + expf(-lp[NE - 1]));
        float* gp = gd + (size_t)(m0 + tok) * 64 + hh * 8;
#pragma unroll
        for (int e = 0; e < NE; ++e)
            gp[e] = (e == best) ? g1 : ((e == NE - 1) ? g2 : 0.f);
    }
}

// ---------------------------------------------------------------------------
// Preprocess: split fp32 -> bf16 hi/lo (no transpose). n divisible by 1024.
// ---------------------------------------------------------------------------
__global__ void split_kernel(const float* __restrict__ src,
                             u16* __restrict__ dh, u16* __restrict__ dl) {
    int i = (blockIdx.x * 256 + threadIdx.x) * 4;
    float4 v = *(const float4*)(src + i);
    u16 h[4], l[4];
    bfsplit(v.x, h[0], l[0]); bfsplit(v.y, h[1], l[1]);
    bfsplit(v.z, h[2], l[2]); bfsplit(v.w, h[3], l[3]);
    uint2 ph = { (unsigned)h[0] | ((unsigned)h[1] << 16),
                 (unsigned)h[2] | ((unsigned)h[3] << 16) };
    uint2 pl = { (unsigned)l[0] | ((unsigned)l[1] << 16),
                 (unsigned)l[2] | ((unsigned)l[3] << 16) };
    *(uint2*)&dh[i] = ph;
    *(uint2*)&dl[i] = pl;
}

// ---------------------------------------------------------------------------
// Preprocess: per-matrix transpose + split. src[mat][R][C] -> dst[mat][C][R].
// ---------------------------------------------------------------------------
__global__ void tsplit_kernel(const float* __restrict__ src,
                              u16* __restrict__ dh, u16* __restrict__ dl,
                              int R, int C) {
    __shared__ float tile[32][33];
    const int mat = blockIdx.x;
    const int r0 = blockIdx.y * 32, c0 = blockIdx.z * 32;
    const size_t base = (size_t)mat * R * C;
    const int tr = threadIdx.x >> 5, tc = threadIdx.x & 31;
#pragma unroll
    for (int p = 0; p < 4; ++p)
        tile[tr + p * 8][tc] = src[base + (size_t)(r0 + tr + p * 8) * C + c0 + tc];
    __syncthreads();
#pragma unroll
    for (int p = 0; p < 4; ++p) {
        int cc = tr + p * 8, rr = tc;
        float x = tile[rr][cc];
        u16 hh, ll; bfsplit(x, hh, ll);
        size_t o = base + (size_t)(c0 + cc) * R + r0 + rr;
        dh[o] = hh; dl[o] = ll;
    }
}

// ---------------------------------------------------------------------------
// Value CVMM, split-bf16 MFMA, dense over experts.
// ---------------------------------------------------------------------------
__global__ __launch_bounds__(256, 2) void v_mfma_kernel(
        const u16* __restrict__ Ah_g, const u16* __restrict__ Al_g,
        const u16* __restrict__ Bh_g, const u16* __restrict__ Bl_g,
        const float* __restrict__ gdense,
        float* __restrict__ wv) {
    const int i0 = blockIdx.x * 128;
    const int h  = blockIdx.y;
    __shared__ u16 Ah[128 * 64], Al[128 * 64], Bh[128 * 64], Bl[128 * 64];
    __shared__ float gl[128 * 8];
    const int t = threadIdx.x;
    const int lane = t & 63, wave = t >> 6;
    const int wm = wave >> 1, wn = wave & 1;
    const int ln = lane & 15, qd = lane >> 4;
    const f4v z4 = {0.f, 0.f, 0.f, 0.f};

#pragma unroll
    for (int p = 0; p < 4; ++p) {
        int idx = p * 256 + t;
        gl[idx] = gdense[(size_t)(i0 + (idx >> 3)) * 64 + h * 8 + (idx & 7)];
    }

    f4v C[4][4];
#pragma unroll
    for (int fm = 0; fm < 4; ++fm)
#pragma unroll
        for (int fn = 0; fn < 4; ++fn) C[fm][fn] = z4;

    for (int e = 0; e < 8; ++e) {
        f4v T[4][4];
#pragma unroll
        for (int fm = 0; fm < 4; ++fm)
#pragma unroll
            for (int fn = 0; fn < 4; ++fn) T[fm][fn] = z4;
        const size_t bbase = (size_t)(h * 8 + e) * DH * 1024;
        for (int kb = 0; kb < 16; ++kb) {
            __syncthreads();
            const int kbase = kb * 64;
#pragma unroll
            for (int p = 0; p < 4; ++p) {
                int chunk = p * 256 + t;
                int row = chunk >> 3;
                int cs  = ((chunk & 7) ^ (row & 7)) * 8;
                int ld  = (p * 256 + (t & 192)) * 8;
                size_t ga = (size_t)(i0 + row) * 1024 + kbase + cs;
                gll16(&Ah_g[ga], &Ah[ld]);
                gll16(&Al_g[ga], &Al[ld]);
                size_t gb = bbase + (size_t)row * 1024 + kbase + cs;
                gll16(&Bh_g[gb], &Bh[ld]);
                gll16(&Bl_g[gb], &Bl[ld]);
            }
            __syncthreads();
#pragma unroll
            for (int ks = 0; ks < 2; ++ks) {
                s8v ah[4], alv[4], bh[4], blv[4];
#pragma unroll
                for (int fm = 0; fm < 4; ++fm) {
                    int o = swzoff(wm * 64 + fm * 16 + ln, ks * 4 + qd);
                    ah[fm]  = *(const s8v*)&Ah[o];
                    alv[fm] = *(const s8v*)&Al[o];
                }
#pragma unroll
                for (int fn = 0; fn < 4; ++fn) {
                    int o = swzoff(wn * 64 + fn * 16 + ln, ks * 4 + qd);
                    bh[fn]  = *(const s8v*)&Bh[o];
                    blv[fn] = *(const s8v*)&Bl[o];
                }
#pragma unroll
                for (int fm = 0; fm < 4; ++fm)
#pragma unroll
                    for (int fn = 0; fn < 4; ++fn) {
                        T[fm][fn] = MFMA16(ah[fm],  bh[fn],  T[fm][fn]);
                        T[fm][fn] = MFMA16(ah[fm],  blv[fn], T[fm][fn]);
                        T[fm][fn] = MFMA16(alv[fm], bh[fn],  T[fm][fn]);
                    }
            }
        }
#pragma unroll
        for (int fm = 0; fm < 4; ++fm)
#pragma unroll
            for (int r = 0; r < 4; ++r) {
                float g = gl[(wm * 64 + fm * 16 + qd * 4 + r) * 8 + e];
#pragma unroll
                for (int fn = 0; fn < 4; ++fn)
                    C[fm][fn][r] += g * T[fm][fn][r];
            }
    }
#pragma unroll
    for (int fm = 0; fm < 4; ++fm)
#pragma unroll
        for (int fn = 0; fn < 4; ++fn)
#pragma unroll
            for (int r = 0; r < 4; ++r) {
                int token = i0 + wm * 64 + fm * 16 + qd * 4 + r;
                int f = wn * 64 + fn * 16 + ln;
                int b = token >> 11, s = token & 2047;
                wv[(((size_t)(b * NH + h) * SS + s) << 7) + f] = C[fm][fn][r];
            }
}

// ---------------------------------------------------------------------------
// Output CVMM, split-bf16 MFMA, dense over (h,e). XCD-aware 1D grid (512):
// the 8 blocks sharing an A-tile land on one XCD -> A fetched once per L2.
// ---------------------------------------------------------------------------
__global__ __launch_bounds__(256, 2) void out_mfma_kernel(
        const u16* __restrict__ Ah_g, const u16* __restrict__ Al_g,
        const u16* __restrict__ Bh_g, const u16* __restrict__ Bl_g,
        const float* __restrict__ gdense,
        float* __restrict__ out) {
    const int id = blockIdx.x;               // 0..511
    const int xcd = id & 7, j = id >> 3;
    const int it = xcd * 8 + (j & 7);        // i-tile 0..63 (8 per XCD)
    const int nt = j >> 3;                   // n-tile 0..7
    const int n0 = nt * 128;
    const int i0 = it * 128;
    __shared__ u16 Ah[128 * 64], Al[128 * 64], Bh[128 * 64], Bl[128 * 64];
    __shared__ float gl[128 * 8];
    const int t = threadIdx.x;
    const int lane = t & 63, wave = t >> 6;
    const int wm = wave >> 1, wn = wave & 1;
    const int ln = lane & 15, qd = lane >> 4;
    const f4v z4 = {0.f, 0.f, 0.f, 0.f};

    f4v C[4][4];
#pragma unroll
    for (int fm = 0; fm < 4; ++fm)
#pragma unroll
        for (int fn = 0; fn < 4; ++fn) C[fm][fn] = z4;

    for (int h = 0; h < 8; ++h) {
        __syncthreads();
#pragma unroll
        for (int p = 0; p < 4; ++p) {
            int idx = p * 256 + t;
            gl[idx] = gdense[(size_t)(i0 + (idx >> 3)) * 64 + h * 8 + (idx & 7)];
        }
        for (int e = 0; e < 8; ++e) {
            f4v T[4][4];
#pragma unroll
            for (int fm = 0; fm < 4; ++fm)
#pragma unroll
                for (int fn = 0; fn < 4; ++fn) T[fm][fn] = z4;
            const size_t bbase = ((size_t)(h * 8 + e) * 1024 + n0) * DH;
#pragma unroll
            for (int kb = 0; kb < 2; ++kb) {
                __syncthreads();
                const int ka = h * 128 + kb * 64;
                const int kbb = kb * 64;
#pragma unroll
                for (int p = 0; p < 4; ++p) {
                    int chunk = p * 256 + t;
                    int row = chunk >> 3;
                    int cs  = ((chunk & 7) ^ (row & 7)) * 8;
                    int ld  = (p * 256 + (t & 192)) * 8;
                    size_t ga = (size_t)(i0 + row) * 1024 + ka + cs;
                    gll16(&Ah_g[ga], &Ah[ld]);
                    gll16(&Al_g[ga], &Al[ld]);
                    size_t gb = bbase + (size_t)row * DH + kbb + cs;
                    gll16(&Bh_g[gb], &Bh[ld]);
                    gll16(&Bl_g[gb], &Bl[ld]);
                }
                __syncthreads();
#pragma unroll
                for (int ks = 0; ks < 2; ++ks) {
                    s8v ah[4], alv[4], bh[4], blv[4];
#pragma unroll
                    for (int fm = 0; fm < 4; ++fm) {
                        int o = swzoff(wm * 64 + fm * 16 + ln, ks * 4 + qd);
                        ah[fm]  = *(const s8v*)&Ah[o];
                        alv[fm] = *(const s8v*)&Al[o];
                    }
#pragma unroll
                    for (int fn = 0; fn < 4; ++fn) {
                        int o = swzoff(wn * 64 + fn * 16 + ln, ks * 4 + qd);
                        bh[fn]  = *(const s8v*)&Bh[o];
                        blv[fn] = *(const s8v*)&Bl[o];
                    }
#pragma unroll
                    for (int fm = 0; fm < 4; ++fm)
#pragma unroll
                        for (int fn = 0; fn < 4; ++fn) {
                            T[fm][fn] = MFMA16(ah[fm],  bh[fn],  T[fm][fn]);
                            T[fm][fn] = MFMA16(ah[fm],  blv[fn], T[fm][fn]);
                            T[fm][fn] = MFMA16(alv[fm], bh[fn],  T[fm][fn]);
                        }
                }
            }
#pragma unroll
            for (int fm = 0; fm < 4; ++fm)
#pragma unroll
                for (int r = 0; r < 4; ++r) {
                    float g = gl[(wm * 64 + fm * 16 + qd * 4 + r) * 8 + e];
#pragma unroll
                    for (int fn = 0; fn < 4; ++fn)
                        C[fm][fn][r] += g * T[fm][fn][r];
                }
        }
    }
#pragma unroll
    for (int fm = 0; fm < 4; ++fm)
#pragma unroll
        for (int fn = 0; fn < 4; ++fn)
#pragma unroll
            for (int r = 0; r < 4; ++r) {
                int token = i0 + wm * 64 + fm * 16 + qd * 4 + r;
                int d = n0 + wn * 64 + fn * 16 + ln;
                out[(size_t)token * DM + d] = C[fm][fn][r];
            }
}

// ---------------------------------------------------------------------------
// MFMA flash attention (unchanged from round 5).
// ---------------------------------------------------------------------------
__global__ __launch_bounds__(256, 2) void attn_mfma_kernel(
        const u16* __restrict__ qh, const u16* __restrict__ ql,
        const u16* __restrict__ kh, const u16* __restrict__ kl,
        const u16* __restrict__ vth, const u16* __restrict__ vtl,
        u16* __restrict__ res_hi, u16* __restrict__ res_lo) {
    const int bid = blockIdx.x;          // bh*16 + qtile
    const int bh = bid >> 4;
    const int q0 = (bid & 15) * 128;

    __shared__ u16 Ksh[32 * 136];        // 8704 B
    __shared__ u16 Ksl[32 * 136];
    __shared__ u16 Vsh[128 * 40];        // 10240 B
    __shared__ u16 Vsl[128 * 40];
    __shared__ u16 Ps[4][32 * 40];       // 10240 B  -> total 48128 B

    const int t = threadIdx.x;
    const int lane = t & 63, w = t >> 6;
    const int ln = lane & 15, qd = lane >> 4;

    // Q A-fragments in registers: 2 row-blocks of 16 (m = ln within block)
    s8v Qh[2][4], Qlv[2][4];
#pragma unroll
    for (int fm = 0; fm < 2; ++fm) {
        const size_t qoff = ((size_t)bh * SS + q0 + w * 32 + fm * 16 + ln) * DH;
        const u16* qhp = qh + qoff;
        const u16* qlp = ql + qoff;
#pragma unroll
        for (int ks = 0; ks < 4; ++ks) {
            Qh[fm][ks]  = *(const s8v*)(qhp + ks * 32 + qd * 8);
            Qlv[fm][ks] = *(const s8v*)(qlp + ks * 32 + qd * 8);
        }
    }

    f4v Of[2][8];
    const f4v z4 = {0.f, 0.f, 0.f, 0.f};
#pragma unroll
    for (int fm = 0; fm < 2; ++fm)
#pragma unroll
        for (int fn = 0; fn < 8; ++fn) Of[fm][fn] = z4;
    float mrow[2][4], lrow[2][4];
#pragma unroll
    for (int fm = 0; fm < 2; ++fm)
#pragma unroll
        for (int r = 0; r < 4; ++r) { mrow[fm][r] = -INFINITY; lrow[fm][r] = 0.f; }

    const u16* kbh = kh + (size_t)bh * SS * DH;
    const u16* kbl = kl + (size_t)bh * SS * DH;
    const u16* vbh = vth + (size_t)bh * DH * SS;   // [f][s]
    const u16* vbl = vtl + (size_t)bh * DH * SS;

    // per-thread staging addresses (chunk = t and chunk = 256+t)
    const int krow0 = t >> 4,        kc0 = t & 15;
    const int krow1 = (256 + t) >> 4, kc1 = (256 + t) & 15;
    const int vrow0 = t >> 2,        vc0 = t & 3;
    const int vrow1 = (256 + t) >> 2, vc1 = (256 + t) & 3;
    const int kld0 = krow0 * 136 + kc0 * 8, kld1 = krow1 * 136 + kc1 * 8;
    const int vld0 = vrow0 * 40 + vc0 * 8,  vld1 = vrow1 * 40 + vc1 * 8;

    // staging registers — NAMED scalars, straight-line code (no arrays)
    uint4 rKh0, rKh1, rKl0, rKl1, rVh0, rVh1, rVl0, rVl1;

#define LOADREGS(KT)                                                         \
    {                                                                        \
        size_t g0 = (size_t)((KT) * 32 + krow0) * DH + kc0 * 8;              \
        size_t g1 = (size_t)((KT) * 32 + krow1) * DH + kc1 * 8;              \
        rKh0 = *(const uint4*)&kbh[g0];  rKl0 = *(const uint4*)&kbl[g0];     \
        rKh1 = *(const uint4*)&kbh[g1];  rKl1 = *(const uint4*)&kbl[g1];     \
        size_t v0 = (size_t)vrow0 * SS + (KT) * 32 + vc0 * 8;                \
        size_t v1 = (size_t)vrow1 * SS + (KT) * 32 + vc1 * 8;                \
        rVh0 = *(const uint4*)&vbh[v0];  rVl0 = *(const uint4*)&vbl[v0];     \
        rVh1 = *(const uint4*)&vbh[v1];  rVl1 = *(const uint4*)&vbl[v1];     \
    }

#define STORELDS()                                                           \
    {                                                                        \
        *(uint4*)&Ksh[kld0] = rKh0;  *(uint4*)&Ksl[kld0] = rKl0;             \
        *(uint4*)&Ksh[kld1] = rKh1;  *(uint4*)&Ksl[kld1] = rKl1;             \
        *(uint4*)&Vsh[vld0] = rVh0;  *(uint4*)&Vsl[vld0] = rVl0;             \
        *(uint4*)&Vsh[vld1] = rVh1;  *(uint4*)&Vsl[vld1] = rVl1;             \
    }

    // prologue: stage tile 0
    LOADREGS(0);
    STORELDS();
    __syncthreads();

    for (int kt = 0; kt < SS / 32; ++kt) {
        const bool more = (kt + 1 < SS / 32);
        if (more) LOADREGS(kt + 1);       // in flight during compute

        // ---- QK^T: S[fm][nt], K frags shared across the 2 row-blocks ----
        f4v S[2][2];
#pragma unroll
        for (int fm = 0; fm < 2; ++fm)
#pragma unroll
            for (int nt = 0; nt < 2; ++nt) S[fm][nt] = z4;
#pragma unroll
        for (int ks = 0; ks < 4; ++ks) {
#pragma unroll
            for (int nt = 0; nt < 2; ++nt) {
                int o = (nt * 16 + ln) * 136 + ks * 32 + qd * 8;
                s8v kbhf = *(const s8v*)&Ksh[o];
                s8v kblf = *(const s8v*)&Ksl[o];
#pragma unroll
                for (int fm = 0; fm < 2; ++fm) {
                    S[fm][nt] = MFMA16(Qh[fm][ks],  kbhf, S[fm][nt]);
                    S[fm][nt] = MFMA16(Qh[fm][ks],  kblf, S[fm][nt]);
                    S[fm][nt] = MFMA16(Qlv[fm][ks], kbhf, S[fm][nt]);
                }
            }
        }

        // ---- online softmax (two independent row-blocks -> ILP) ----
        float pv[2][2][4];
#pragma unroll
        for (int fm = 0; fm < 2; ++fm) {
            float mt[4];
#pragma unroll
            for (int r = 0; r < 4; ++r) mt[r] = fmaxf(S[fm][0][r], S[fm][1][r]);
#pragma unroll
            for (int mask = 1; mask < 16; mask <<= 1)
#pragma unroll
                for (int r = 0; r < 4; ++r)
                    mt[r] = fmaxf(mt[r], __shfl_xor(mt[r], mask, 64));
            float alpha[4];
#pragma unroll
            for (int r = 0; r < 4; ++r) {
                float mn = fmaxf(mrow[fm][r], mt[r]);
                alpha[r] = __expf(mrow[fm][r] - mn);
                mrow[fm][r] = mn;
            }
            float lt[4] = {0.f, 0.f, 0.f, 0.f};
#pragma unroll
            for (int nt = 0; nt < 2; ++nt)
#pragma unroll
                for (int r = 0; r < 4; ++r) {
                    float p = __expf(S[fm][nt][r] - mrow[fm][r]);
                    pv[fm][nt][r] = p;
                    lt[r] += p;
                }
#pragma unroll
            for (int mask = 1; mask < 16; mask <<= 1)
#pragma unroll
                for (int r = 0; r < 4; ++r)
                    lt[r] += __shfl_xor(lt[r], mask, 64);
#pragma unroll
            for (int r = 0; r < 4; ++r)
                lrow[fm][r] = alpha[r] * lrow[fm][r] + lt[r];
#pragma unroll
            for (int fn = 0; fn < 8; ++fn)
#pragma unroll
                for (int r = 0; r < 4; ++r) Of[fm][fn][r] *= alpha[r];
        }

        // ---- P (C-layout) -> per-wave LDS (A-layout source) ----
#pragma unroll
        for (int fm = 0; fm < 2; ++fm)
#pragma unroll
            for (int nt = 0; nt < 2; ++nt)
#pragma unroll
                for (int r = 0; r < 4; ++r)
                    Ps[w][(fm * 16 + qd * 4 + r) * 40 + nt * 16 + ln] =
                        bf16rne(pv[fm][nt][r]);
        // same-wave write->read: compiler inserts lgkmcnt wait; no barrier.

        // ---- PV: Of += P * V, V frags shared across the 2 row-blocks ----
        s8v pf[2];
#pragma unroll
        for (int fm = 0; fm < 2; ++fm)
            pf[fm] = *(const s8v*)&Ps[w][(fm * 16 + ln) * 40 + qd * 8];
#pragma unroll
        for (int fn = 0; fn < 8; ++fn) {
            int o = (fn * 16 + ln) * 40 + qd * 8;
            s8v vbhf = *(const s8v*)&Vsh[o];
            s8v vblf = *(const s8v*)&Vsl[o];
#pragma unroll
            for (int fm = 0; fm < 2; ++fm) {
                Of[fm][fn] = MFMA16(pf[fm], vbhf, Of[fm][fn]);
                Of[fm][fn] = MFMA16(pf[fm], vblf, Of[fm][fn]);
            }
        }

        __syncthreads();                  // all waves done reading K/V LDS
        if (more) {
            STORELDS();                   // waits vmcnt for rK/rV arrival
            __syncthreads();              // next tile staged
        }
    }

    // ---- epilogue: normalize, split to bf16 hi/lo, store res[token][1024] --
    const int b = bh >> 3, h = bh & 7;
#pragma unroll
    for (int fm = 0; fm < 2; ++fm)
#pragma unroll
        for (int r = 0; r < 4; ++r) {
            float linv = 1.f / lrow[fm][r];
            int qi = q0 + w * 32 + fm * 16 + qd * 4 + r;
            size_t off = (size_t)(b * SS + qi) * DM + h * DH + ln;
#pragma unroll
            for (int fn = 0; fn < 8; ++fn) {
                u16 hh, ll;
                bfsplit(Of[fm][fn][r] * linv, hh, ll);
                res_hi[off + fn * 16] = hh;
                res_lo[off + fn * 16] = ll;
            }
        }
#undef LOADREGS
#undef STORELDS
}

// ---------------------------------------------------------------------------
extern "C" void kernel_launch(void* const* d_in, const int* in_sizes, int n_in,
                              void* d_out, int out_size, void* d_ws, size_t ws_size,
                              hipStream_t stream) {
    (void)in_sizes; (void)n_in; (void)out_size; (void)ws_size;
    const float* q_src = (const float*)d_in[0];
    const float* k_src = (const float*)d_in[1];
    const float* v_src = (const float*)d_in[2];
    const float* Wq    = (const float*)d_in[3];
    const float* Wk    = (const float*)d_in[4];
    const float* V     = (const float*)d_in[5];
    const float* O     = (const float*)d_in[6];
    const float* sel_v = (const float*)d_in[7];
    const float* sel_o = (const float*)d_in[8];
    float* out = (float*)d_out;

    // workspace layout
    const size_t NELT = (size_t)NTOK * DM;   // 8388608
    u16* wq_h = (u16*)d_ws;                  // q hi/lo [bh][s][f]
    u16* wq_l = wq_h + NELT;
    u16* wk_h = wq_l + NELT;                 // k hi/lo
    u16* wk_l = wk_h + NELT;
    float* wv = (float*)(wk_l + NELT);       // v fp32 [bh][s][f]
    u16* res_hi = (u16*)(wv + NELT);         // attention result hi/lo
    u16* res_lo = res_hi + NELT;
    u16* vs_hi  = res_lo + NELT;             // vsrc split (later: Ot)
    u16* vs_lo  = vs_hi + NELT;
    u16* Vt_hi  = vs_lo + NELT;              // V transposed (later: vT)
    u16* Vt_lo  = Vt_hi + NELT;
    float* gv = (float*)(Vt_lo + NELT);      // dense gates [8192][64]
    float* go = gv + (size_t)NTOK * 64;
    u16* Wq_h = (u16*)(go + (size_t)NTOK * 64);  // W splits (1024x1024 each)
    u16* Wq_l = Wq_h + (size_t)DM * DM;
    u16* Wk_h = Wq_l + (size_t)DM * DM;
    u16* Wk_l = Wk_h + (size_t)DM * DM;
    // aliases (regions dead during the phase they are used)
    u16* qsrc_h = res_hi;                    // dead until attn writes res
    u16* qsrc_l = res_lo;
    u16* ksrc_h = (u16*)wv;                  // dead until v_mfma writes wv
    u16* ksrc_l = ksrc_h + NELT;
    u16* Ot_hi = vs_hi;                      // alias (dead after v_mfma)
    u16* Ot_lo = vs_lo;
    u16* vth   = Vt_hi;                      // alias (dead after v_mfma)
    u16* vtl   = Vt_lo;

    // preprocess: splits
    split_kernel<<<NELT / 1024, 256, 0, stream>>>(v_src, vs_hi, vs_lo);
    split_kernel<<<NELT / 1024, 256, 0, stream>>>(q_src, qsrc_h, qsrc_l);
    split_kernel<<<NELT / 1024, 256, 0, stream>>>(k_src, ksrc_h, ksrc_l);
    split_kernel<<<(DM * DM) / 1024, 256, 0, stream>>>(Wq, Wq_h, Wq_l);
    split_kernel<<<(DM * DM) / 1024, 256, 0, stream>>>(Wk, Wk_h, Wk_l);
    tsplit_kernel<<<dim3(64, 32, 4), 256, 0, stream>>>(V, Vt_hi, Vt_lo, 1024, 128);

    // gates: fused GEMM-tiled logits + argmax/sigmoid epilogue (both gates
    // in one launch; grid (128 token-tiles, 2 gates))
    gate_fused_kernel<<<dim3(128, 2), 256, 0, stream>>>(
        k_src, sel_v, gv, q_src, sel_o, go);

    // q/k projections via MFMA (emit bf16 hi/lo)
    proj_mfma_kernel<<<dim3(64, 8), 256, 0, stream>>>(
        qsrc_h, qsrc_l, Wq_h, Wq_l, wq_h, wq_l, SCALE_SQRT);
    proj_mfma_kernel<<<dim3(64, 8), 256, 0, stream>>>(
        ksrc_h, ksrc_l, Wk_h, Wk_l, wk_h, wk_l, SCALE_SQRT);

    // value CVMM (MFMA, dense) -> wv fp32 (overwrites ksrc splits: proj done)
    v_mfma_kernel<<<dim3(64, 8), 256, 0, stream>>>(vs_hi, vs_lo, Vt_hi, Vt_lo, gv, wv);

    // transpose+split O into dead vsrc buffers
    tsplit_kernel<<<dim3(64, 4, 32), 256, 0, stream>>>(O, Ot_hi, Ot_lo, 128, 1024);

    // transpose+split v into dead Vt buffers: vT[bh][f][s]
    tsplit_kernel<<<dim3(32, 64, 4), 256, 0, stream>>>(wv, vth, vtl, 2048, 128);

    // attention (MFMA flash; 128-query tiles; writes res = overwrites qsrc)
    attn_mfma_kernel<<<BB * NH * (SS / 128), 256, 0, stream>>>(
        wq_h, wq_l, wk_h, wk_l, vth, vtl, res_hi, res_lo);

    // output CVMM (MFMA, dense; XCD-swizzled 1D grid)
    out_mfma_kernel<<<512, 256, 0, stream>>>(res_hi, res_lo, Ot_hi, Ot_lo, go, out);
}